// Round 3
// baseline (39.047 us; speedup 1.0000x reference)
//
#include <hip/hip_runtime.h>
#include <hip/hip_cooperative_groups.h>

namespace cg = cooperative_groups;

#define KN 4096
#define NSAMP 16384

// One fused cooperative kernel: 16 blocks x 1024 threads.
//  Phase A: coeffs for all 16384 neurons (1 per thread), written to d_ws.
//  Phase B: block b = input pattern b; 4-layer network in LDS; table[b] -> d_ws.
//  Phase C: 1 sample per thread; double table lookup with exact update logic.
__global__ __launch_bounds__(1024) void fused_all(
    const float* __restrict__ x,
    const float* __restrict__ w0, const float* __restrict__ wsG,
    const int* __restrict__ ia0, const int* __restrict__ ib0,
    const int* __restrict__ ia, const int* __restrict__ ib,
    float4* __restrict__ coeffs, float* __restrict__ table,
    float* __restrict__ out) {
    cg::grid_group grid = cg::this_grid();
    __shared__ float h0[KN];
    __shared__ float h1[KN];
    __shared__ float red[2][16];
    __shared__ float tbl[32];
    const int tid = threadIdx.x;
    const int pat = blockIdx.x;
    const int g = pat * 1024 + tid;   // global thread id == neuron id == sample id

    // ---------------- Phase A: softmax -> 4 multilinear coeffs ----------------
    {
        const float* wp = (g < KN) ? (w0 + (size_t)g * 16)
                                   : (wsG + (size_t)(g - KN) * 16);
        const float4* wr = (const float4*)wp;
        float4 v0 = wr[0], v1 = wr[1], v2 = wr[2], v3 = wr[3];
        // weights ~ N(0,1): |w| < ~6, expf cannot overflow -> skip max-subtract.
        float e0 = __expf(v0.x), e1 = __expf(v0.y), e2 = __expf(v0.z), e3 = __expf(v0.w);
        float e4 = __expf(v1.x), e5 = __expf(v1.y), e6 = __expf(v1.z), e7 = __expf(v1.w);
        float e8 = __expf(v2.x), e9 = __expf(v2.y), e10 = __expf(v2.z), e11 = __expf(v2.w);
        float e12 = __expf(v3.x), e13 = __expf(v3.y), e14 = __expf(v3.z), e15 = __expf(v3.w);
        float s = ((e0 + e1) + (e2 + e3)) + ((e4 + e5) + (e6 + e7))
                + ((e8 + e9) + (e10 + e11)) + ((e12 + e13) + (e14 + e15));
        float can  = ((e2 + e3) + (e6 + e7)) - ((e8 + e9) + (e12 + e13));
        float cbn  = ((e4 + e5) + (e6 + e7)) - ((e8 + e9) + (e10 + e11));
        float cabn = (e1 - e2) - (e4 + e7) - 2.0f * e6 + (e8 + e11) + 2.0f * e9
                   + (e13 - e14);
        float c0n  = ((e8 + e9) + (e10 + e11)) + ((e12 + e13) + (e14 + e15));
        float inv = 1.0f / s;
        coeffs[g] = make_float4(c0n * inv, can * inv, cbn * inv, cabn * inv);
    }
    grid.sync();

    // ---------------- Phase B: per-pattern network ----------------
    // Layer 0: inputs are the 4 pattern bits.
    #pragma unroll
    for (int i = 0; i < 4; ++i) {
        int k = tid + i * 1024;
        float4 c = coeffs[k];
        float a = (float)((pat >> ia0[k]) & 1);
        float b = (float)((pat >> ib0[k]) & 1);
        h0[k] = c.x + c.y * a + c.z * b + c.w * (a * b);
    }
    __syncthreads();

#define LAYER(L, SRC, DST)                                                    \
    {                                                                         \
        const int* ial = ia + (L) * KN;                                       \
        const int* ibl = ib + (L) * KN;                                       \
        _Pragma("unroll")                                                     \
        for (int i = 0; i < 4; ++i) {                                         \
            int k = tid + i * 1024;                                           \
            float4 c = coeffs[((L) + 1) * KN + k];                            \
            float a = SRC[ial[k]];                                            \
            float b = SRC[ibl[k]];                                            \
            DST[k] = c.x + c.y * a + c.z * b + c.w * (a * b);                 \
        }                                                                     \
        __syncthreads();                                                      \
    }
    LAYER(0, h0, h1)
    LAYER(1, h1, h0)
    LAYER(2, h0, h1)
#undef LAYER

    // Class sums: k in [0,2048) -> class 0, else class 1. TAU = 1.
    {
        float s0 = h1[tid] + h1[tid + 1024];
        float s1 = h1[tid + 2048] + h1[tid + 3072];
        #pragma unroll
        for (int off = 32; off > 0; off >>= 1) {
            s0 += __shfl_down(s0, off, 64);
            s1 += __shfl_down(s1, off, 64);
        }
        int wid = tid >> 6, lane = tid & 63;
        if (lane == 0) { red[0][wid] = s0; red[1][wid] = s1; }
        __syncthreads();
        if (tid == 0) {
            float t0 = 0.0f, t1 = 0.0f;
            #pragma unroll
            for (int wq = 0; wq < 16; ++wq) { t0 += red[0][wq]; t1 += red[1][wq]; }
            table[pat * 2 + 0] = t0;
            table[pat * 2 + 1] = t1;
        }
    }
    grid.sync();

    // ---------------- Phase C: classify (1 sample per thread) ----------------
    if (tid < 32) tbl[tid] = table[tid];
    __syncthreads();
    {
        float2 xv = ((const float2*)x)[g];
        float mx[4] = { xv.x, xv.y, -xv.x, -xv.y };
        int p0 = 0;
        float ivf[4];
        #pragma unroll
        for (int i = 0; i < 4; ++i) {
            int b = mx[i] > 0.0f;
            ivf[i] = (float)b;
            p0 |= b << i;
        }
        float r0 = tbl[p0 * 2 + 0];
        float r1 = tbl[p0 * 2 + 1];
        int lastl = (r1 > r0) ? 1 : 0;           // argmax, tie -> 0
        float thresh = lastl ? 0.5f : -0.5f;
        int p1 = 0;
        #pragma unroll
        for (int i = 0; i < 4; ++i) {
            bool upd = (ivf[i] == r0) || (ivf[i] == r1);   // any(flags == 0)
            int bit = upd ? (int)(mx[i] > thresh) : (int)ivf[i];
            p1 |= bit << i;
        }
        float2 o;
        o.x = tbl[p1 * 2 + 0];
        o.y = tbl[p1 * 2 + 1];
        ((float2*)out)[g] = o;
    }
}

extern "C" void kernel_launch(void* const* d_in, const int* in_sizes, int n_in,
                              void* d_out, int out_size, void* d_ws, size_t ws_size,
                              hipStream_t stream) {
    const float* x   = (const float*)d_in[0];
    const float* w0  = (const float*)d_in[1];
    const float* wsG = (const float*)d_in[2];
    const int* ia0   = (const int*)d_in[3];
    const int* ib0   = (const int*)d_in[4];
    const int* ia    = (const int*)d_in[5];
    const int* ib    = (const int*)d_in[6];
    float* out       = (float*)d_out;

    float* table   = (float*)d_ws;                    // 32 floats
    float4* coeffs = (float4*)((char*)d_ws + 256);    // 16384 float4 = 256 KB

    void* args[] = { (void*)&x, (void*)&w0, (void*)&wsG,
                     (void*)&ia0, (void*)&ib0, (void*)&ia, (void*)&ib,
                     (void*)&coeffs, (void*)&table, (void*)&out };
    hipLaunchCooperativeKernel((void*)fused_all, dim3(16), dim3(1024),
                               args, 0, stream);
}

// Round 4
// 21.576 us; speedup vs baseline: 1.8097x; 1.8097x over previous
//
#include <hip/hip_runtime.h>

#define KN 4096
#define NSAMP 16384

// Device-scope spin barrier for a 16-block grid (all blocks co-resident:
// 16 blocks x 1024 thr, 1 block/CU on a 256-CU chip). Only thread 0 arrives
// and polls (RMW -> executes at the coherence point, no stale-cache risk);
// the rest of the block parks at __syncthreads. ctr must be 0 at call start
// (kernel_launch memsets it each call).
__device__ __forceinline__ void grid_barrier(unsigned* ctr) {
    __syncthreads();
    if (threadIdx.x == 0) {
        __threadfence();
        __hip_atomic_fetch_add(ctr, 1u, __ATOMIC_ACQ_REL, __HIP_MEMORY_SCOPE_AGENT);
        while (__hip_atomic_fetch_add(ctr, 0u, __ATOMIC_ACQ_REL,
                                      __HIP_MEMORY_SCOPE_AGENT) < 16u) { }
        __threadfence();
    }
    __syncthreads();
}

// One fused kernel, regular launch: 16 blocks x 1024 threads.
//  Phase A: coeffs for all 16384 neurons (1 per thread) -> d_ws.   [barrier]
//  Phase B: block b = input pattern b; 4-layer net in LDS; table.  [barrier]
//  Phase C: 1 sample per thread; double table lookup, exact update logic.
__global__ __launch_bounds__(1024) void fused_all(
    const float* __restrict__ x,
    const float* __restrict__ w0, const float* __restrict__ wsG,
    const int* __restrict__ ia0, const int* __restrict__ ib0,
    const int* __restrict__ ia, const int* __restrict__ ib,
    unsigned* __restrict__ ctr, float4* __restrict__ coeffs,
    float* __restrict__ table, float* __restrict__ out) {
    __shared__ float h0[KN];
    __shared__ float h1[KN];
    __shared__ float red[2][16];
    __shared__ float tbl[32];
    const int tid = threadIdx.x;
    const int pat = blockIdx.x;
    const int g = pat * 1024 + tid;   // global id == neuron id == sample id

    // ---------------- Phase A: softmax -> 4 multilinear coeffs ----------------
    {
        const float* wp = (g < KN) ? (w0 + (size_t)g * 16)
                                   : (wsG + (size_t)(g - KN) * 16);
        const float4* wr = (const float4*)wp;
        float4 v0 = wr[0], v1 = wr[1], v2 = wr[2], v3 = wr[3];
        // weights ~ N(0,1): expf cannot overflow -> skip max-subtract.
        float e0 = __expf(v0.x), e1 = __expf(v0.y), e2 = __expf(v0.z), e3 = __expf(v0.w);
        float e4 = __expf(v1.x), e5 = __expf(v1.y), e6 = __expf(v1.z), e7 = __expf(v1.w);
        float e8 = __expf(v2.x), e9 = __expf(v2.y), e10 = __expf(v2.z), e11 = __expf(v2.w);
        float e12 = __expf(v3.x), e13 = __expf(v3.y), e14 = __expf(v3.z), e15 = __expf(v3.w);
        float s = ((e0 + e1) + (e2 + e3)) + ((e4 + e5) + (e6 + e7))
                + ((e8 + e9) + (e10 + e11)) + ((e12 + e13) + (e14 + e15));
        float can  = ((e2 + e3) + (e6 + e7)) - ((e8 + e9) + (e12 + e13));
        float cbn  = ((e4 + e5) + (e6 + e7)) - ((e8 + e9) + (e10 + e11));
        float cabn = (e1 - e2) - (e4 + e7) - 2.0f * e6 + (e8 + e11) + 2.0f * e9
                   + (e13 - e14);
        float c0n  = ((e8 + e9) + (e10 + e11)) + ((e12 + e13) + (e14 + e15));
        float inv = 1.0f / s;
        coeffs[g] = make_float4(c0n * inv, can * inv, cbn * inv, cabn * inv);
    }
    grid_barrier(ctr + 0);

    // ---------------- Phase B: per-pattern network ----------------
    #pragma unroll
    for (int i = 0; i < 4; ++i) {
        int k = tid + i * 1024;
        float4 c = coeffs[k];
        float a = (float)((pat >> ia0[k]) & 1);
        float b = (float)((pat >> ib0[k]) & 1);
        h0[k] = c.x + c.y * a + c.z * b + c.w * (a * b);
    }
    __syncthreads();

#define LAYER(L, SRC, DST)                                                    \
    {                                                                         \
        const int* ial = ia + (L) * KN;                                       \
        const int* ibl = ib + (L) * KN;                                       \
        _Pragma("unroll")                                                     \
        for (int i = 0; i < 4; ++i) {                                         \
            int k = tid + i * 1024;                                           \
            float4 c = coeffs[((L) + 1) * KN + k];                            \
            float a = SRC[ial[k]];                                            \
            float b = SRC[ibl[k]];                                            \
            DST[k] = c.x + c.y * a + c.z * b + c.w * (a * b);                 \
        }                                                                     \
        __syncthreads();                                                      \
    }
    LAYER(0, h0, h1)
    LAYER(1, h1, h0)
    LAYER(2, h0, h1)
#undef LAYER

    // Class sums: k in [0,2048) -> class 0, else class 1. TAU = 1.
    {
        float s0 = h1[tid] + h1[tid + 1024];
        float s1 = h1[tid + 2048] + h1[tid + 3072];
        #pragma unroll
        for (int off = 32; off > 0; off >>= 1) {
            s0 += __shfl_down(s0, off, 64);
            s1 += __shfl_down(s1, off, 64);
        }
        int wid = tid >> 6, lane = tid & 63;
        if (lane == 0) { red[0][wid] = s0; red[1][wid] = s1; }
        __syncthreads();
        if (tid == 0) {
            float t0 = 0.0f, t1 = 0.0f;
            #pragma unroll
            for (int wq = 0; wq < 16; ++wq) { t0 += red[0][wq]; t1 += red[1][wq]; }
            table[pat * 2 + 0] = t0;
            table[pat * 2 + 1] = t1;
        }
    }
    grid_barrier(ctr + 1);

    // ---------------- Phase C: classify (1 sample per thread) ----------------
    if (tid < 32) tbl[tid] = table[tid];
    __syncthreads();
    {
        float2 xv = ((const float2*)x)[g];
        float mx[4] = { xv.x, xv.y, -xv.x, -xv.y };
        int p0 = 0;
        float ivf[4];
        #pragma unroll
        for (int i = 0; i < 4; ++i) {
            int b = mx[i] > 0.0f;
            ivf[i] = (float)b;
            p0 |= b << i;
        }
        float r0 = tbl[p0 * 2 + 0];
        float r1 = tbl[p0 * 2 + 1];
        int lastl = (r1 > r0) ? 1 : 0;           // argmax, tie -> 0
        float thresh = lastl ? 0.5f : -0.5f;
        int p1 = 0;
        #pragma unroll
        for (int i = 0; i < 4; ++i) {
            bool upd = (ivf[i] == r0) || (ivf[i] == r1);   // any(flags == 0)
            int bit = upd ? (int)(mx[i] > thresh) : (int)ivf[i];
            p1 |= bit << i;
        }
        float2 o;
        o.x = tbl[p1 * 2 + 0];
        o.y = tbl[p1 * 2 + 1];
        ((float2*)out)[g] = o;
    }
}

extern "C" void kernel_launch(void* const* d_in, const int* in_sizes, int n_in,
                              void* d_out, int out_size, void* d_ws, size_t ws_size,
                              hipStream_t stream) {
    const float* x   = (const float*)d_in[0];
    const float* w0  = (const float*)d_in[1];
    const float* wsG = (const float*)d_in[2];
    const int* ia0   = (const int*)d_in[3];
    const int* ib0   = (const int*)d_in[4];
    const int* ia    = (const int*)d_in[5];
    const int* ib    = (const int*)d_in[6];
    float* out       = (float*)d_out;

    unsigned* ctr  = (unsigned*)d_ws;                 // 2 barrier counters
    float* table   = (float*)((char*)d_ws + 128);     // 32 floats
    float4* coeffs = (float4*)((char*)d_ws + 512);    // 16384 float4 = 256 KB

    hipMemsetAsync(ctr, 0, 8, stream);                // barrier init, every call
    fused_all<<<16, 1024, 0, stream>>>(x, w0, wsG, ia0, ib0, ia, ib,
                                       ctr, coeffs, table, out);
}